// Round 1
// baseline (570.141 us; speedup 1.0000x reference)
//
#include <hip/hip_runtime.h>
#include <math.h>
#include <stdint.h>

typedef __bf16 bf16_t;
typedef __bf16 bf16x8 __attribute__((ext_vector_type(8)));
typedef __bf16 bf16x4 __attribute__((ext_vector_type(4)));
typedef float f32x4 __attribute__((ext_vector_type(4)));
typedef short s16x8 __attribute__((ext_vector_type(8)));

#define TOKS 2048
#define INF 2048
#define JNF 8192
#define ONF 2048

// ---------------- async staging helpers (BK=64) ----------------
// Tile: ROWS x 64 k bf16, unpadded (row stride 64 elems = 128 B).
// Chunks of 16 B; chunk c: row = c>>3, slot = c&7; slot holds source
// k-quad (slot ^ (row&7)). Fragment ds_read_b128: <=2-way bank alias (free,
// m136). global_load_lds writes lane-contiguous 16B. [conflicts==0 verified]

template <int ROWS, int NT>
__device__ __forceinline__ void stage_async_t(const bf16_t* __restrict__ src, size_t ld,
                                              bf16_t* lds, int tid) {
  constexpr int IT = ROWS * 8 / NT;
#pragma unroll
  for (int r = 0; r < IT; ++r) {
    int c = r * NT + tid;
    int row = c >> 3;
    int kq = (c & 7) ^ (row & 7);
    const bf16_t* g = src + (size_t)row * ld + kq * 8;
    bf16_t* l = lds + (size_t)(r * NT + (tid & ~63)) * 8;  // wave-uniform base
    __builtin_amdgcn_global_load_lds((const __attribute__((address_space(1))) void*)g,
                                     (__attribute__((address_space(3))) void*)l,
                                     16, 0, 0);
  }
}

__device__ __forceinline__ bf16x8 frag_ld64(const bf16_t* lds, int row, int kq) {
  int slot = kq ^ (row & 7);
  return *(const bf16x8*)&lds[row * 64 + slot * 8];
}

// ---------------- prep kernels ----------------

__global__ __launch_bounds__(256) void prep_mu_thr(
    const float* __restrict__ med, const float* __restrict__ aad,
    const float* __restrict__ gth, float debiaser,
    float* __restrict__ mu, float* __restrict__ thr, bf16_t* __restrict__ thrb) {
  int gid = blockIdx.x * 256 + threadIdx.x;  // 65536 threads
  if (gid < INF) mu[gid] = med[gid] * debiaser;
  int i = gid & (INF - 1);
  float stdv = aad[i] * debiaser / 2.5066282746310002f;  // sqrt(2*pi)
  float tv = gth[gid] * stdv * 45.254833995939045f;      // sqrt(2048)
  thr[gid] = tv;
  thrb[gid] = (bf16_t)tv;
}

// One block per token: bf16 casts of x and (x-mu), plus exact fp32 active count.
__global__ __launch_bounds__(256) void prep_x_count(
    const float* __restrict__ x, const float* __restrict__ mu,
    const float* __restrict__ thr,
    bf16_t* __restrict__ xb, bf16_t* __restrict__ xdb,
    float* __restrict__ dense, float* __restrict__ active) {
  int t = blockIdx.x;
  int tid = threadIdx.x;
  int i0 = tid * 8;
  const float* xrow = x + (size_t)t * INF;
  f32x4 x0 = *(const f32x4*)&xrow[i0];
  f32x4 x1 = *(const f32x4*)&xrow[i0 + 4];
  f32x4 m0 = *(const f32x4*)&mu[i0];
  f32x4 m1 = *(const f32x4*)&mu[i0 + 4];
  f32x4 d0 = x0 - m0, d1 = x1 - m1;
  bf16x8 ox, od;
  ox[0] = (bf16_t)x0[0]; ox[1] = (bf16_t)x0[1]; ox[2] = (bf16_t)x0[2]; ox[3] = (bf16_t)x0[3];
  ox[4] = (bf16_t)x1[0]; ox[5] = (bf16_t)x1[1]; ox[6] = (bf16_t)x1[2]; ox[7] = (bf16_t)x1[3];
  od[0] = (bf16_t)d0[0]; od[1] = (bf16_t)d0[1]; od[2] = (bf16_t)d0[2]; od[3] = (bf16_t)d0[3];
  od[4] = (bf16_t)d1[0]; od[5] = (bf16_t)d1[1]; od[6] = (bf16_t)d1[2]; od[7] = (bf16_t)d1[3];
  *(bf16x8*)&xb[(size_t)t * INF + i0] = ox;
  *(bf16x8*)&xdb[(size_t)t * INF + i0] = od;
  f32x4 a0, a1;
  a0[0] = fabsf(d0[0]); a0[1] = fabsf(d0[1]); a0[2] = fabsf(d0[2]); a0[3] = fabsf(d0[3]);
  a1[0] = fabsf(d1[0]); a1[1] = fabsf(d1[1]); a1[2] = fabsf(d1[2]); a1[3] = fabsf(d1[3]);
  int cnt = 0;
#pragma unroll 4
  for (int n = 0; n < 32; ++n) {
    f32x4 t0 = *(const f32x4*)&thr[(n << 11) + i0];
    f32x4 t1 = *(const f32x4*)&thr[(n << 11) + i0 + 4];
    cnt += (a0[0] > t0[0]) + (a0[1] > t0[1]) + (a0[2] > t0[2]) + (a0[3] > t0[3]);
    cnt += (a1[0] > t1[0]) + (a1[1] > t1[1]) + (a1[2] > t1[2]) + (a1[3] > t1[3]);
  }
  for (int off = 32; off; off >>= 1) cnt += __shfl_down(cnt, off);
  __shared__ int red[4];
  int wv = tid >> 6;
  if ((tid & 63) == 0) red[wv] = cnt;
  __syncthreads();
  if (tid == 0) {
    int tot = red[0] + red[1] + red[2] + red[3];
    active[t] = 256.0f * (float)tot;
    dense[t] = 16777216.0f;
  }
}

// src [INF, JNF] fp32 -> dst [JNF, INF] bf16; z selects (gw,uw)
__global__ __launch_bounds__(256) void transpose_cast_dual(
    const float* __restrict__ src0, bf16_t* __restrict__ dst0,
    const float* __restrict__ src1, bf16_t* __restrict__ dst1) {
  const float* src = blockIdx.z ? src1 : src0;
  bf16_t* dst = blockIdx.z ? dst1 : dst0;
  __shared__ float tile[32][33];
  int j0 = blockIdx.x * 32;
  int i0 = blockIdx.y * 32;
  int r = threadIdx.x >> 3;
  int c = (threadIdx.x & 7) * 4;
  f32x4 v = *(const f32x4*)&src[(i0 + r) * JNF + j0 + c];
  tile[r][c] = v[0]; tile[r][c + 1] = v[1]; tile[r][c + 2] = v[2]; tile[r][c + 3] = v[3];
  __syncthreads();
  bf16x4 o;
  o[0] = (bf16_t)tile[c + 0][r];
  o[1] = (bf16_t)tile[c + 1][r];
  o[2] = (bf16_t)tile[c + 2][r];
  o[3] = (bf16_t)tile[c + 3][r];
  *(bf16x4*)&dst[(j0 + r) * INF + i0 + c] = o;
}

__global__ __launch_bounds__(256) void cast_bf16(
    const float* __restrict__ src, bf16_t* __restrict__ dst) {
  int idx = (blockIdx.x * 256 + threadIdx.x) * 8;
  f32x4 a = *(const f32x4*)&src[idx];
  f32x4 b = *(const f32x4*)&src[idx + 4];
  bf16x8 o;
  o[0] = (bf16_t)a[0]; o[1] = (bf16_t)a[1]; o[2] = (bf16_t)a[2]; o[3] = (bf16_t)a[3];
  o[4] = (bf16_t)b[0]; o[5] = (bf16_t)b[1]; o[6] = (bf16_t)b[2]; o[7] = (bf16_t)b[3];
  *(bf16x8*)&dst[idx] = o;
}

// c[j] = gb[j] + sum_i gwT[j,i]*mu[i]; one wave per j-row, no atomics.
__global__ __launch_bounds__(256) void c_from_gwT(
    const bf16_t* __restrict__ gwT, const float* __restrict__ mu,
    const float* __restrict__ gb, float* __restrict__ c) {
  int j = blockIdx.x * 4 + (threadIdx.x >> 6);
  int lane = threadIdx.x & 63;
  float s = 0.f;
#pragma unroll
  for (int it = 0; it < 4; ++it) {
    int i = it * 512 + lane * 8;
    bf16x8 w = *(const bf16x8*)&gwT[(size_t)j * INF + i];
    f32x4 m0 = *(const f32x4*)&mu[i];
    f32x4 m1 = *(const f32x4*)&mu[i + 4];
    s += (float)w[0] * m0[0] + (float)w[1] * m0[1] + (float)w[2] * m0[2] + (float)w[3] * m0[3];
    s += (float)w[4] * m1[0] + (float)w[5] * m1[1] + (float)w[6] * m1[2] + (float)w[7] * m1[3];
  }
  for (int off = 32; off; off >>= 1) s += __shfl_down(s, off);
  if (lane == 0) c[j] = gb[j] + s;
}

// ---------------- unified 256x256 8-phase GEMM (T3+T4+T5) ----------------
// MODE 0: up   — A=xb  (gload_lds), B=upT, epilogue silu(g)*(<acc>+ub) -> h (bf16)
// MODE 1: down — A=h   (gload_lds), B=dwb, split-K z, epilogue f32 -> part
// MODE 2: gate — A=masked xdb (reg-stage, T14 split), B=gwT, epilogue +cj -> g (bf16)
//
// 8 waves (2M x 4N), per-wave output 128x64, acc[8][4] f32x4 (128 VGPR).
// Double-buffered LDS 128 KiB. Per K-tile: 4 phases x {4-12 ds_read_b128,
// barrier, setprio(1), 16 MFMA, setprio(0), barrier}; next tile's staging
// issued entirely at phase 0 (latency hidden under 4 phases of compute);
// ONE vmcnt/lgkm drain per K-tile at the boundary (not per phase).

template <int MODE>
__global__ __launch_bounds__(512) void gemm256(
    const bf16_t* __restrict__ Ag, const bf16_t* __restrict__ Bg,
    const bf16_t* __restrict__ thrv, const float* __restrict__ cvec,
    const bf16_t* __restrict__ gmat, bf16_t* __restrict__ outb,
    float* __restrict__ outf) {
  constexpr int NTILES = 32;  // all modes span K=2048 per block
  constexpr size_t LD = (MODE == 1) ? (size_t)JNF : (size_t)INF;
  __shared__ bf16_t Al[2][256 * 64];  // 64 KB
  __shared__ bf16_t Bl[2][256 * 64];  // 64 KB
  int tid = threadIdx.x;
  int lane = tid & 63;
  int wv = tid >> 6;
  int wm = wv >> 2;  // 0..1 (row group, 128 rows)
  int wn = wv & 3;   // 0..3 (col group, 64 cols)
  int m16 = lane & 15, q = lane >> 4;
  int t0 = blockIdx.y * 256;
  int j0 = blockIdx.x * 256;
  int kbeg = (MODE == 1) ? blockIdx.z * 2048 : 0;
  const bf16_t* Arow = Ag + (size_t)t0 * LD + kbeg;
  const bf16_t* Brow = Bg + (size_t)j0 * LD + kbeg;
  const bf16_t* Tn = (MODE == 2) ? thrv + (size_t)blockIdx.x * INF : (const bf16_t*)nullptr;
  const s16x8 ABS = {0x7FFF, 0x7FFF, 0x7FFF, 0x7FFF, 0x7FFF, 0x7FFF, 0x7FFF, 0x7FFF};

  f32x4 acc[8][4] = {};

  // ---- prologue: tile 0 -> buf 0 ----
  stage_async_t<256, 512>(Brow, LD, Bl[0], tid);
  if constexpr (MODE == 2) {
    s16x8 av0[4], tv0[4];
#pragma unroll
    for (int r2 = 0; r2 < 4; ++r2) {
      int ch = r2 * 512 + tid;
      int row = ch >> 3;
      int kq = (ch & 7) ^ (row & 7);
      av0[r2] = *(const s16x8*)&Arow[(size_t)row * LD + kq * 8];
      tv0[r2] = *(const s16x8*)&Tn[kq * 8];
    }
#pragma unroll
    for (int r2 = 0; r2 < 4; ++r2) {
      int ch = r2 * 512 + tid;
      int row = ch >> 3;
      int sl = ch & 7;
      s16x8 m = (s16x8)((tv0[r2] - (av0[r2] & ABS)) >> 15);
      *(s16x8*)&Al[0][row * 64 + sl * 8] = av0[r2] & m;
    }
  } else {
    stage_async_t<256, 512>(Arow, LD, Al[0], tid);
  }
  asm volatile("s_waitcnt vmcnt(0) lgkmcnt(0)" ::: "memory");
  __builtin_amdgcn_s_barrier();

  for (int u = 0; u < NTILES; ++u) {
    int c = u & 1;
    const bf16_t* Ab = Al[c];
    const bf16_t* Bb = Bl[c];
    bf16x8 bfr[4][2];
    s16x8 av[4], tv[4];  // MODE 2 only (DCE'd otherwise)
#pragma unroll
    for (int p = 0; p < 4; ++p) {
      if (p == 0) {
        // issue next tile's staging into the free buffer (hidden under 4 phases)
        if (u + 1 < NTILES) {
          stage_async_t<256, 512>(Brow + (u + 1) * 64, LD, Bl[c ^ 1], tid);
          if constexpr (MODE == 2) {
            int k0 = (u + 1) * 64;
#pragma unroll
            for (int r2 = 0; r2 < 4; ++r2) {
              int ch = r2 * 512 + tid;
              int row = ch >> 3;
              int kq = (ch & 7) ^ (row & 7);
              av[r2] = *(const s16x8*)&Arow[(size_t)row * LD + k0 + kq * 8];
              tv[r2] = *(const s16x8*)&Tn[k0 + kq * 8];
            }
          } else {
            stage_async_t<256, 512>(Arow + (u + 1) * 64, LD, Al[c ^ 1], tid);
          }
        }
        // B fragments for the whole tile (held in regs across phases)
#pragma unroll
        for (int ni = 0; ni < 4; ++ni)
#pragma unroll
          for (int ks = 0; ks < 2; ++ks)
            bfr[ni][ks] = frag_ld64(Bb, wn * 64 + ni * 16 + m16, ks * 4 + q);
      }
      bf16x8 af[2][2];
#pragma unroll
      for (int mi2 = 0; mi2 < 2; ++mi2)
#pragma unroll
        for (int ks = 0; ks < 2; ++ks)
          af[mi2][ks] = frag_ld64(Ab, wm * 128 + (p * 2 + mi2) * 16 + m16, ks * 4 + q);
      if constexpr (MODE == 2) {
        // T14 write-late: mask + ds_write 2 phases after the issue
        if (p == 2 && u + 1 < NTILES) {
#pragma unroll
          for (int r2 = 0; r2 < 4; ++r2) {
            int ch = r2 * 512 + tid;
            int row = ch >> 3;
            int sl = ch & 7;
            s16x8 m = (s16x8)((tv[r2] - (av[r2] & ABS)) >> 15);
            *(s16x8*)&Al[c ^ 1][row * 64 + sl * 8] = av[r2] & m;
          }
        }
      }
      __builtin_amdgcn_s_barrier();
      __builtin_amdgcn_s_setprio(1);
#pragma unroll
      for (int mi2 = 0; mi2 < 2; ++mi2)
#pragma unroll
        for (int ni = 0; ni < 4; ++ni)
#pragma unroll
          for (int ks = 0; ks < 2; ++ks)
            acc[p * 2 + mi2][ni] = __builtin_amdgcn_mfma_f32_16x16x32_bf16(
                af[mi2][ks], bfr[ni][ks], acc[p * 2 + mi2][ni], 0, 0, 0);
      __builtin_amdgcn_s_setprio(0);
      if (p < 3) __builtin_amdgcn_s_barrier();
    }
    // K-tile boundary: single drain (next tile's loads had 4 phases to land)
    asm volatile("s_waitcnt vmcnt(0) lgkmcnt(0)" ::: "memory");
    __builtin_amdgcn_s_barrier();
  }

  // ---- epilogue ----
  int cb = j0 + wn * 64;
  int rb = t0 + wm * 128;
  if constexpr (MODE == 1) {
    float* dst = outf + (size_t)blockIdx.z * ((size_t)TOKS * ONF);
#pragma unroll
    for (int mi = 0; mi < 8; ++mi)
#pragma unroll
      for (int ni = 0; ni < 4; ++ni) {
        int col = cb + ni * 16 + m16;
#pragma unroll
        for (int r = 0; r < 4; ++r) {
          int row = rb + mi * 16 + q * 4 + r;
          dst[(size_t)row * ONF + col] = acc[mi][ni][r];
        }
      }
  } else if constexpr (MODE == 0) {
#pragma unroll
    for (int mi = 0; mi < 8; ++mi)
#pragma unroll
      for (int ni = 0; ni < 4; ++ni) {
        int col = cb + ni * 16 + m16;
        float bias = cvec[col];
#pragma unroll
        for (int r = 0; r < 4; ++r) {
          int row = rb + mi * 16 + q * 4 + r;
          float upv = acc[mi][ni][r] + bias;
          float gv = (float)gmat[(size_t)row * JNF + col];
          float hv = (gv / (1.f + expf(-gv))) * upv;
          outb[(size_t)row * JNF + col] = (bf16_t)hv;
        }
      }
  } else {
#pragma unroll
    for (int mi = 0; mi < 8; ++mi)
#pragma unroll
      for (int ni = 0; ni < 4; ++ni) {
        int col = cb + ni * 16 + m16;
        float cadd = cvec[col];
#pragma unroll
        for (int r = 0; r < 4; ++r) {
          int row = rb + mi * 16 + q * 4 + r;
          outb[(size_t)row * JNF + col] = (bf16_t)(acc[mi][ni][r] + cadd);
        }
      }
  }
}

__global__ __launch_bounds__(256) void down_reduce(
    const float* __restrict__ part, const float* __restrict__ db,
    float* __restrict__ y) {
  int idx = (blockIdx.x * 256 + threadIdx.x) * 4;
  f32x4 a = *(const f32x4*)&part[idx];
  f32x4 b = *(const f32x4*)&part[idx + 4194304];
  f32x4 c = *(const f32x4*)&part[idx + 2 * 4194304];
  f32x4 d = *(const f32x4*)&part[idx + 3 * 4194304];
  f32x4 bias = *(const f32x4*)&db[idx & (ONF - 1)];
  *(f32x4*)&y[idx] = a + b + c + d + bias;
}

// ---------------- launcher ----------------

extern "C" void kernel_launch(void* const* d_in, const int* in_sizes, int n_in,
                              void* d_out, int out_size, void* d_ws, size_t ws_size,
                              hipStream_t stream) {
  (void)in_sizes; (void)n_in; (void)out_size; (void)ws_size;
  const float* x   = (const float*)d_in[0];
  const float* gw  = (const float*)d_in[1];
  const float* gb  = (const float*)d_in[2];
  const float* gth = (const float*)d_in[3];
  const float* med = (const float*)d_in[4];
  const float* aad = (const float*)d_in[5];
  const float* uw  = (const float*)d_in[6];
  const float* ub  = (const float*)d_in[7];
  const float* dw  = (const float*)d_in[8];
  const float* db  = (const float*)d_in[9];

  float* out = (float*)d_out;
  float* y = out;                       // [2048,2048]
  float* dense = out + 4194304;         // [2048]
  float* active = dense + 2048;         // [2048]

  char* ws = (char*)d_ws;
  float*  mu   = (float*)(ws + 0);           //   8 KB
  float*  thr  = (float*)(ws + 8192);        // 256 KB (fp32, exact count)
  bf16_t* thrb = (bf16_t*)(ws + 270336);     // 128 KB (bf16 bits)
  float*  cj   = (float*)(ws + 401408);      //  32 KB
  bf16_t* xb   = (bf16_t*)(ws + 434176);     //   8 MB
  bf16_t* xdb  = (bf16_t*)(ws + 8822784);    //   8 MB
  bf16_t* gwT  = (bf16_t*)(ws + 17211392);   //  32 MB
  bf16_t* upT  = (bf16_t*)(ws + 50765824);   //  32 MB
  bf16_t* dwb  = (bf16_t*)(ws + 84320256);   //  32 MB
  bf16_t* hb   = (bf16_t*)(ws + 117874688);  //  32 MB
  float*  part = (float*)(ws + 151429120);   //  64 MB -> total ~218.5 MB
  bf16_t* gb16 = (bf16_t*)part;  // alias: g dead before down_gemm writes part

  float debiaser = (float)(1.0 / (1e-7 + (1.0 - pow(0.99, 1000.0))));

  prep_mu_thr<<<256, 256, 0, stream>>>(med, aad, gth, debiaser, mu, thr, thrb);
  prep_x_count<<<2048, 256, 0, stream>>>(x, mu, thr, xb, xdb, dense, active);
  transpose_cast_dual<<<dim3(256, 64, 2), 256, 0, stream>>>(gw, gwT, uw, upT);
  cast_bf16<<<8192, 256, 0, stream>>>(dw, dwb);
  c_from_gwT<<<2048, 256, 0, stream>>>(gwT, mu, gb, cj);
  gemm256<2><<<dim3(32, 8), 512, 0, stream>>>(xdb, gwT, thrb, cj, nullptr, gb16, nullptr);
  gemm256<0><<<dim3(32, 8), 512, 0, stream>>>(xb, upT, nullptr, ub, gb16, hb, nullptr);
  gemm256<1><<<dim3(8, 8, 4), 512, 0, stream>>>(hb, dwb, nullptr, nullptr, nullptr, nullptr, part);
  down_reduce<<<4096, 256, 0, stream>>>(part, db, y);
}

// Round 2
// 482.004 us; speedup vs baseline: 1.1829x; 1.1829x over previous
//
#include <hip/hip_runtime.h>
#include <math.h>
#include <stdint.h>

typedef __bf16 bf16_t;
typedef __bf16 bf16x8 __attribute__((ext_vector_type(8)));
typedef __bf16 bf16x4 __attribute__((ext_vector_type(4)));
typedef float f32x4 __attribute__((ext_vector_type(4)));
typedef short s16x8 __attribute__((ext_vector_type(8)));

#define TOKS 2048
#define INF 2048
#define JNF 8192
#define ONF 2048

#define VMW(N) asm volatile("s_waitcnt vmcnt(" #N ")" ::: "memory")
#define LGKM0 asm volatile("s_waitcnt lgkmcnt(0)" ::: "memory")
#define BAR __builtin_amdgcn_s_barrier()

// ---------------- staging helpers (BK=64, half-tile = 128 rows) ----------
// Tile: rows x 64 k bf16, unpadded (row stride 64 elems = 128 B).
// Chunks of 16 B; chunk c: row = c>>3, slot = c&7; slot holds source
// k-quad (slot ^ (row&7)). Fragment ds_read_b128: <=2-way bank alias (free).
// global_load_lds writes lane-contiguous 16B. [conflicts==0 verified R1]

// One half-tile: 128 rows x 64 k = 16 KB = 512 thr x 2 chunks x 16 B.
__device__ __forceinline__ void stage_half(const bf16_t* __restrict__ src, size_t ld,
                                           bf16_t* lds, int tid) {
#pragma unroll
  for (int r = 0; r < 2; ++r) {
    int c = r * 512 + tid;
    int row = c >> 3;
    int kq = (c & 7) ^ (row & 7);
    const bf16_t* g = src + (size_t)row * ld + kq * 8;
    bf16_t* l = lds + (size_t)(r * 512 + (tid & ~63)) * 8;  // wave-uniform base
    __builtin_amdgcn_global_load_lds((const __attribute__((address_space(1))) void*)g,
                                     (__attribute__((address_space(3))) void*)l,
                                     16, 0, 0);
  }
}

__device__ __forceinline__ bf16x8 frag_ld64(const bf16_t* lds, int row, int kq) {
  int slot = kq ^ (row & 7);
  return *(const bf16x8*)&lds[row * 64 + slot * 8];
}

__device__ __forceinline__ void ds_bf(const bf16_t* B, int wn, int m16, int q,
                                      bf16x8 (&bfr)[4][2]) {
#pragma unroll
  for (int ni = 0; ni < 4; ++ni)
#pragma unroll
    for (int ks = 0; ks < 2; ++ks)
      bfr[ni][ks] = frag_ld64(B, wn * 64 + ni * 16 + m16, ks * 4 + q);
}

template <int P>
__device__ __forceinline__ void ds_af(const bf16_t* A, int wm, int m16, int q,
                                      bf16x8 (&af)[2][2]) {
#pragma unroll
  for (int mi2 = 0; mi2 < 2; ++mi2)
#pragma unroll
    for (int ks = 0; ks < 2; ++ks)
      af[mi2][ks] = frag_ld64(A, wm * 128 + P * 32 + mi2 * 16 + m16, ks * 4 + q);
}

template <int P>
__device__ __forceinline__ void mfma_ph(f32x4 (&acc)[8][4], const bf16x8 (&af)[2][2],
                                        const bf16x8 (&bfr)[4][2]) {
  __builtin_amdgcn_s_barrier();
  __builtin_amdgcn_s_setprio(1);
#pragma unroll
  for (int mi2 = 0; mi2 < 2; ++mi2)
#pragma unroll
    for (int ni = 0; ni < 4; ++ni)
#pragma unroll
      for (int ks = 0; ks < 2; ++ks)
        acc[P * 2 + mi2][ni] = __builtin_amdgcn_mfma_f32_16x16x32_bf16(
            af[mi2][ks], bfr[ni][ks], acc[P * 2 + mi2][ni], 0, 0, 0);
  __builtin_amdgcn_s_setprio(0);
}

// MODE 2 masked-A reg staging: 4 x 16B loads per half (2 av + 2 tv)
__device__ __forceinline__ void loadA_half(const bf16_t* __restrict__ Arow, size_t ld,
                                           const bf16_t* __restrict__ Tn, int k0, int half,
                                           int tid, s16x8 (&av)[2], s16x8 (&tv)[2]) {
#pragma unroll
  for (int r = 0; r < 2; ++r) {
    int c = r * 512 + tid;
    int lrow = c >> 3;
    int kq = (c & 7) ^ (lrow & 7);
    av[r] = *(const s16x8*)&Arow[(size_t)(half * 128 + lrow) * ld + k0 + kq * 8];
    tv[r] = *(const s16x8*)&Tn[k0 + kq * 8];
  }
}

__device__ __forceinline__ void writeA_half(bf16_t* halfbase, int tid,
                                            const s16x8 (&av)[2], const s16x8 (&tv)[2]) {
  const s16x8 ABS = {0x7FFF, 0x7FFF, 0x7FFF, 0x7FFF, 0x7FFF, 0x7FFF, 0x7FFF, 0x7FFF};
#pragma unroll
  for (int r = 0; r < 2; ++r) {
    int c = r * 512 + tid;
    int lrow = c >> 3;
    int sl = c & 7;
    s16x8 m = (s16x8)((tv[r] - (av[r] & ABS)) >> 15);
    *(s16x8*)&halfbase[lrow * 64 + sl * 8] = av[r] & m;
  }
}

// ---------------- prep kernels ----------------

__global__ __launch_bounds__(256) void prep_mu_thr(
    const float* __restrict__ med, const float* __restrict__ aad,
    const float* __restrict__ gth, float debiaser,
    float* __restrict__ mu, float* __restrict__ thr, bf16_t* __restrict__ thrb) {
  int gid = blockIdx.x * 256 + threadIdx.x;  // 65536 threads
  if (gid < INF) mu[gid] = med[gid] * debiaser;
  int i = gid & (INF - 1);
  float stdv = aad[i] * debiaser / 2.5066282746310002f;  // sqrt(2*pi)
  float tv = gth[gid] * stdv * 45.254833995939045f;      // sqrt(2048)
  thr[gid] = tv;
  thrb[gid] = (bf16_t)tv;
}

// One block per token: bf16 casts of x and (x-mu), plus exact fp32 active count.
__global__ __launch_bounds__(256) void prep_x_count(
    const float* __restrict__ x, const float* __restrict__ mu,
    const float* __restrict__ thr,
    bf16_t* __restrict__ xb, bf16_t* __restrict__ xdb,
    float* __restrict__ dense, float* __restrict__ active) {
  int t = blockIdx.x;
  int tid = threadIdx.x;
  int i0 = tid * 8;
  const float* xrow = x + (size_t)t * INF;
  f32x4 x0 = *(const f32x4*)&xrow[i0];
  f32x4 x1 = *(const f32x4*)&xrow[i0 + 4];
  f32x4 m0 = *(const f32x4*)&mu[i0];
  f32x4 m1 = *(const f32x4*)&mu[i0 + 4];
  f32x4 d0 = x0 - m0, d1 = x1 - m1;
  bf16x8 ox, od;
  ox[0] = (bf16_t)x0[0]; ox[1] = (bf16_t)x0[1]; ox[2] = (bf16_t)x0[2]; ox[3] = (bf16_t)x0[3];
  ox[4] = (bf16_t)x1[0]; ox[5] = (bf16_t)x1[1]; ox[6] = (bf16_t)x1[2]; ox[7] = (bf16_t)x1[3];
  od[0] = (bf16_t)d0[0]; od[1] = (bf16_t)d0[1]; od[2] = (bf16_t)d0[2]; od[3] = (bf16_t)d0[3];
  od[4] = (bf16_t)d1[0]; od[5] = (bf16_t)d1[1]; od[6] = (bf16_t)d1[2]; od[7] = (bf16_t)d1[3];
  *(bf16x8*)&xb[(size_t)t * INF + i0] = ox;
  *(bf16x8*)&xdb[(size_t)t * INF + i0] = od;
  f32x4 a0, a1;
  a0[0] = fabsf(d0[0]); a0[1] = fabsf(d0[1]); a0[2] = fabsf(d0[2]); a0[3] = fabsf(d0[3]);
  a1[0] = fabsf(d1[0]); a1[1] = fabsf(d1[1]); a1[2] = fabsf(d1[2]); a1[3] = fabsf(d1[3]);
  int cnt = 0;
#pragma unroll 4
  for (int n = 0; n < 32; ++n) {
    f32x4 t0 = *(const f32x4*)&thr[(n << 11) + i0];
    f32x4 t1 = *(const f32x4*)&thr[(n << 11) + i0 + 4];
    cnt += (a0[0] > t0[0]) + (a0[1] > t0[1]) + (a0[2] > t0[2]) + (a0[3] > t0[3]);
    cnt += (a1[0] > t1[0]) + (a1[1] > t1[1]) + (a1[2] > t1[2]) + (a1[3] > t1[3]);
  }
  for (int off = 32; off; off >>= 1) cnt += __shfl_down(cnt, off);
  __shared__ int red[4];
  int wv = tid >> 6;
  if ((tid & 63) == 0) red[wv] = cnt;
  __syncthreads();
  if (tid == 0) {
    int tot = red[0] + red[1] + red[2] + red[3];
    active[t] = 256.0f * (float)tot;
    dense[t] = 16777216.0f;
  }
}

// src [INF, JNF] fp32 -> dst [JNF, INF] bf16; z selects (gw,uw)
__global__ __launch_bounds__(256) void transpose_cast_dual(
    const float* __restrict__ src0, bf16_t* __restrict__ dst0,
    const float* __restrict__ src1, bf16_t* __restrict__ dst1) {
  const float* src = blockIdx.z ? src1 : src0;
  bf16_t* dst = blockIdx.z ? dst1 : dst0;
  __shared__ float tile[32][33];
  int j0 = blockIdx.x * 32;
  int i0 = blockIdx.y * 32;
  int r = threadIdx.x >> 3;
  int c = (threadIdx.x & 7) * 4;
  f32x4 v = *(const f32x4*)&src[(i0 + r) * JNF + j0 + c];
  tile[r][c] = v[0]; tile[r][c + 1] = v[1]; tile[r][c + 2] = v[2]; tile[r][c + 3] = v[3];
  __syncthreads();
  bf16x4 o;
  o[0] = (bf16_t)tile[c + 0][r];
  o[1] = (bf16_t)tile[c + 1][r];
  o[2] = (bf16_t)tile[c + 2][r];
  o[3] = (bf16_t)tile[c + 3][r];
  *(bf16x4*)&dst[(j0 + r) * INF + i0 + c] = o;
}

__global__ __launch_bounds__(256) void cast_bf16(
    const float* __restrict__ src, bf16_t* __restrict__ dst) {
  int idx = (blockIdx.x * 256 + threadIdx.x) * 8;
  f32x4 a = *(const f32x4*)&src[idx];
  f32x4 b = *(const f32x4*)&src[idx + 4];
  bf16x8 o;
  o[0] = (bf16_t)a[0]; o[1] = (bf16_t)a[1]; o[2] = (bf16_t)a[2]; o[3] = (bf16_t)a[3];
  o[4] = (bf16_t)b[0]; o[5] = (bf16_t)b[1]; o[6] = (bf16_t)b[2]; o[7] = (bf16_t)b[3];
  *(bf16x8*)&dst[idx] = o;
}

// c[j] = gb[j] + sum_i gwT[j,i]*mu[i]; one wave per j-row, no atomics.
__global__ __launch_bounds__(256) void c_from_gwT(
    const bf16_t* __restrict__ gwT, const float* __restrict__ mu,
    const float* __restrict__ gb, float* __restrict__ c) {
  int j = blockIdx.x * 4 + (threadIdx.x >> 6);
  int lane = threadIdx.x & 63;
  float s = 0.f;
#pragma unroll
  for (int it = 0; it < 4; ++it) {
    int i = it * 512 + lane * 8;
    bf16x8 w = *(const bf16x8*)&gwT[(size_t)j * INF + i];
    f32x4 m0 = *(const f32x4*)&mu[i];
    f32x4 m1 = *(const f32x4*)&mu[i + 4];
    s += (float)w[0] * m0[0] + (float)w[1] * m0[1] + (float)w[2] * m0[2] + (float)w[3] * m0[3];
    s += (float)w[4] * m1[0] + (float)w[5] * m1[1] + (float)w[6] * m1[2] + (float)w[7] * m1[3];
  }
  for (int off = 32; off; off >>= 1) s += __shfl_down(s, off);
  if (lane == 0) c[j] = gb[j] + s;
}

// ------------- unified 256x256 8-phase GEMM, COUNTED vmcnt (T3+T4+T5) -------------
// MODE 0: up   — A=xb  (gload_lds), B=upT, epilogue silu(g)*(<acc>+ub) -> h (bf16)
// MODE 1: down — A=h   (gload_lds), B=dwb, split-K z, epilogue f32 -> part
// MODE 2: gate — A=masked xdb (reg-stage + ds_write), B=gwT, epilogue +cj -> g (bf16)
//
// Iteration = 2 K-tiles: a=2i (buf0, ph0-3), b=2i+1 (buf1, ph4-7).
// Half-tile staggered staging, 3-7 phases ahead of use; boundary waits are
// COUNTED (vmcnt(4) gload / vmcnt(12) gate), never 0 in the main loop (T4).
// Per-thread issue sequence per iteration (gload modes, 2 loads/half):
//   ph0: A0(b)  ph1: A1(b),B0(c)  ph2: B1(c)  ph4: A0(c)  ph5: A1(c)
//   ph6: B0(d)  ph7: B1(d);  waits: ph3 vmcnt(4) [need A1(b); newer=B(c)],
//   ph7 vmcnt(4) [need A1(c); newer=B(d)].
// MODE 2: A via reg-loads (4/half, 3 phases ahead) + mask/ds_write into the
// freed half; derived waits ph0:8 ph1:2 ph3:12 ph4:6 ph5:6 ph7:12; every
// ds_write phase drains lgkmcnt(0) before its closing barrier (cross-wave).

template <int MODE>
__global__ __launch_bounds__(512) void gemm256(
    const bf16_t* __restrict__ Ag, const bf16_t* __restrict__ Bg,
    const bf16_t* __restrict__ thrv, const float* __restrict__ cvec,
    const bf16_t* __restrict__ gmat, bf16_t* __restrict__ outb,
    float* __restrict__ outf) {
  constexpr size_t LD = (MODE == 1) ? (size_t)JNF : (size_t)INF;
  constexpr int NIT = 16;  // 32 K-tiles of 64
  __shared__ bf16_t Als[2][256 * 64];  // 64 KB
  __shared__ bf16_t Bls[2][256 * 64];  // 64 KB
  bf16_t* Als0 = Als[0]; bf16_t* Als1 = Als[1];
  bf16_t* Bls0 = Bls[0]; bf16_t* Bls1 = Bls[1];
  int tid = threadIdx.x;
  int lane = tid & 63;
  int wv = tid >> 6;
  int wm = wv >> 2;  // 0..1 row group (128 rows)
  int wn = wv & 3;   // 0..3 col group (64 cols)
  int m16 = lane & 15, q = lane >> 4;
  int t0 = blockIdx.y * 256;
  int j0 = blockIdx.x * 256;
  int kbeg = (MODE == 1) ? blockIdx.z * 2048 : 0;
  const bf16_t* Arow = Ag + (size_t)t0 * LD + kbeg;
  const bf16_t* Brow = Bg + (size_t)j0 * LD + kbeg;
  const bf16_t* Tn = (MODE == 2) ? thrv + (size_t)blockIdx.x * INF : (const bf16_t*)nullptr;

  f32x4 acc[8][4] = {};
  bf16x8 bfr[4][2];
  bf16x8 af[2][2];
  s16x8 avA0[2], tvA0[2], avA1[2], tvA1[2];  // MODE 2 only (DCE'd otherwise)

  // ---- prologue: tile0 full, tile1 B (and MODE2 tile1 A regs) ----
  if constexpr (MODE == 2) {
    loadA_half(Arow, LD, Tn, 0, 0, tid, avA0, tvA0);
    loadA_half(Arow, LD, Tn, 0, 1, tid, avA1, tvA1);
    VMW(0);  // prologue only
    writeA_half(Als0, tid, avA0, tvA0);
    writeA_half(Als0 + 128 * 64, tid, avA1, tvA1);
    LGKM0;
    stage_half(Brow, LD, Bls0, tid);                               // B0(t0) :2
    stage_half(Brow + (size_t)128 * LD, LD, Bls0 + 128 * 64, tid); // B1(t0) :2
    loadA_half(Arow, LD, Tn, 64, 0, tid, avA0, tvA0);              // A0(t1) :4
    stage_half(Brow + 64, LD, Bls1, tid);                          // B0(t1) :2
    loadA_half(Arow, LD, Tn, 64, 1, tid, avA1, tvA1);              // A1(t1) :4
    stage_half(Brow + (size_t)128 * LD + 64, LD, Bls1 + 128 * 64, tid);  // B1(t1) :2
    VMW(12);  // need B(t0); newer = 4+2+4+2
  } else {
    stage_half(Brow, LD, Bls0, tid);
    stage_half(Brow + (size_t)128 * LD, LD, Bls0 + 128 * 64, tid);
    stage_half(Arow, LD, Als0, tid);
    stage_half(Arow + (size_t)128 * LD, LD, Als0 + 128 * 64, tid);
    stage_half(Brow + 64, LD, Bls1, tid);
    stage_half(Brow + (size_t)128 * LD + 64, LD, Bls1 + 128 * 64, tid);
    VMW(4);  // need tile0; newer = B(t1)
  }
  BAR;

  for (int i = 0; i < NIT; ++i) {
    const bool S = (i < NIT - 1);
    const int kb = i * 128;  // tile a k0; b:+64 c:+128 d:+192
    // ---- ph0: quadrant 0 of tile a; stage A0(b) ----
    ds_bf(Bls0, wn, m16, q, bfr);
    ds_af<0>(Als0, wm, m16, q, af);
    if constexpr (MODE == 2) {
      VMW(8);  // need avA0 (prev ph5); newer = prev ph6 (2+4) + ph7 (2)
      writeA_half(Als1, tid, avA0, tvA0);
      LGKM0;
    } else {
      stage_half(Arow + kb + 64, LD, Als1, tid);
    }
    mfma_ph<0>(acc, af, bfr); BAR;
    // ---- ph1: stage A1(b); B0(c); [M2: loadA(c,0)] ----
    ds_af<1>(Als0, wm, m16, q, af);
    if constexpr (MODE == 2) {
      VMW(2);  // need avA1 (prev ph6, after B0(d)); newer = prev ph7 B1(d)
      writeA_half(Als1 + 128 * 64, tid, avA1, tvA1);
      LGKM0;
      if (S) {
        stage_half(Brow + kb + 128, LD, Bls0, tid);
        loadA_half(Arow, LD, Tn, kb + 128, 0, tid, avA0, tvA0);
      }
    } else {
      stage_half(Arow + (size_t)128 * LD + kb + 64, LD, Als1 + 128 * 64, tid);
      if (S) stage_half(Brow + kb + 128, LD, Bls0, tid);
    }
    mfma_ph<1>(acc, af, bfr); BAR;
    // ---- ph2: [M2: loadA(c,1)]; stage B1(c) ----
    ds_af<2>(Als0, wm, m16, q, af);
    if (S) {
      if constexpr (MODE == 2) loadA_half(Arow, LD, Tn, kb + 128, 1, tid, avA1, tvA1);
      stage_half(Brow + (size_t)128 * LD + kb + 128, LD, Bls0 + 128 * 64, tid);
    }
    mfma_ph<2>(acc, af, bfr); BAR;
    // ---- ph3: boundary wait (counted) ----
    ds_af<3>(Als0, wm, m16, q, af);
    mfma_ph<3>(acc, af, bfr);
    if (S) { if constexpr (MODE == 2) { VMW(12); } else { VMW(4); } }
    else   { VMW(0); }
    BAR;
    // ---- ph4: quadrant 0 of tile b; stage/write A0(c) ----
    ds_bf(Bls1, wn, m16, q, bfr);
    ds_af<0>(Als1, wm, m16, q, af);
    if (S) {
      if constexpr (MODE == 2) {
        VMW(6);  // need avA0 (ph1, after B0(c)); newer = ph2 (4+2)
        writeA_half(Als0, tid, avA0, tvA0);
        LGKM0;
      } else {
        stage_half(Arow + kb + 128, LD, Als0, tid);
      }
    }
    mfma_ph<4>(acc, af, bfr); BAR;
    // ---- ph5: [M2: loadA(d,0)]; stage/write A1(c) ----
    ds_af<1>(Als1, wm, m16, q, af);
    if (S) {
      if constexpr (MODE == 2) {
        loadA_half(Arow, LD, Tn, kb + 192, 0, tid, avA0, tvA0);
        VMW(6);  // need avA1 (ph2, before B1(c)); newer = B1(c):2 + loadA(d,0):4
        writeA_half(Als0 + 128 * 64, tid, avA1, tvA1);
        LGKM0;
      } else {
        stage_half(Arow + (size_t)128 * LD + kb + 128, LD, Als0 + 128 * 64, tid);
      }
    }
    mfma_ph<5>(acc, af, bfr); BAR;
    // ---- ph6: stage B0(d); [M2: loadA(d,1)] ----
    ds_af<2>(Als1, wm, m16, q, af);
    if (S) {
      stage_half(Brow + kb + 192, LD, Bls1, tid);
      if constexpr (MODE == 2) loadA_half(Arow, LD, Tn, kb + 192, 1, tid, avA1, tvA1);
    }
    mfma_ph<6>(acc, af, bfr); BAR;
    // ---- ph7: stage B1(d); boundary wait (counted) ----
    ds_af<3>(Als1, wm, m16, q, af);
    if (S) stage_half(Brow + (size_t)128 * LD + kb + 192, LD, Bls1 + 128 * 64, tid);
    mfma_ph<7>(acc, af, bfr);
    if (S) { if constexpr (MODE == 2) { VMW(12); } else { VMW(4); } }
    else   { VMW(0); }
    BAR;
  }

  // ---- epilogue ----
  int cb = j0 + wn * 64;
  int rb = t0 + wm * 128;
  if constexpr (MODE == 1) {
    float* dst = outf + (size_t)blockIdx.z * ((size_t)TOKS * ONF);
#pragma unroll
    for (int mi = 0; mi < 8; ++mi)
#pragma unroll
      for (int ni = 0; ni < 4; ++ni) {
        int col = cb + ni * 16 + m16;
#pragma unroll
        for (int r = 0; r < 4; ++r) {
          int row = rb + mi * 16 + q * 4 + r;
          dst[(size_t)row * ONF + col] = acc[mi][ni][r];
        }
      }
  } else if constexpr (MODE == 0) {
#pragma unroll
    for (int mi = 0; mi < 8; ++mi)
#pragma unroll
      for (int ni = 0; ni < 4; ++ni) {
        int col = cb + ni * 16 + m16;
        float bias = cvec[col];
#pragma unroll
        for (int r = 0; r < 4; ++r) {
          int row = rb + mi * 16 + q * 4 + r;
          float upv = acc[mi][ni][r] + bias;
          float gv = (float)gmat[(size_t)row * JNF + col];
          float hv = (gv / (1.f + expf(-gv))) * upv;
          outb[(size_t)row * JNF + col] = (bf16_t)hv;
        }
      }
  } else {
#pragma unroll
    for (int mi = 0; mi < 8; ++mi)
#pragma unroll
      for (int ni = 0; ni < 4; ++ni) {
        int col = cb + ni * 16 + m16;
        float cadd = cvec[col];
#pragma unroll
        for (int r = 0; r < 4; ++r) {
          int row = rb + mi * 16 + q * 4 + r;
          outb[(size_t)row * JNF + col] = (bf16_t)(acc[mi][ni][r] + cadd);
        }
      }
  }
}

__global__ __launch_bounds__(256) void down_reduce(
    const float* __restrict__ part, const float* __restrict__ db,
    float* __restrict__ y) {
  int idx = (blockIdx.x * 256 + threadIdx.x) * 4;
  f32x4 a = *(const f32x4*)&part[idx];
  f32x4 b = *(const f32x4*)&part[idx + 4194304];
  f32x4 c = *(const f32x4*)&part[idx + 2 * 4194304];
  f32x4 d = *(const f32x4*)&part[idx + 3 * 4194304];
  f32x4 bias = *(const f32x4*)&db[idx & (ONF - 1)];
  *(f32x4*)&y[idx] = a + b + c + d + bias;
}

// ---------------- launcher ----------------

extern "C" void kernel_launch(void* const* d_in, const int* in_sizes, int n_in,
                              void* d_out, int out_size, void* d_ws, size_t ws_size,
                              hipStream_t stream) {
  (void)in_sizes; (void)n_in; (void)out_size; (void)ws_size;
  const float* x   = (const float*)d_in[0];
  const float* gw  = (const float*)d_in[1];
  const float* gb  = (const float*)d_in[2];
  const float* gth = (const float*)d_in[3];
  const float* med = (const float*)d_in[4];
  const float* aad = (const float*)d_in[5];
  const float* uw  = (const float*)d_in[6];
  const float* ub  = (const float*)d_in[7];
  const float* dw  = (const float*)d_in[8];
  const float* db  = (const float*)d_in[9];

  float* out = (float*)d_out;
  float* y = out;                       // [2048,2048]
  float* dense = out + 4194304;         // [2048]
  float* active = dense + 2048;         // [2048]

  char* ws = (char*)d_ws;
  float*  mu   = (float*)(ws + 0);           //   8 KB
  float*  thr  = (float*)(ws + 8192);        // 256 KB (fp32, exact count)
  bf16_t* thrb = (bf16_t*)(ws + 270336);     // 128 KB (bf16 bits)
  float*  cj   = (float*)(ws + 401408);      //  32 KB
  bf16_t* xb   = (bf16_t*)(ws + 434176);     //   8 MB
  bf16_t* xdb  = (bf16_t*)(ws + 8822784);    //   8 MB
  bf16_t* gwT  = (bf16_t*)(ws + 17211392);   //  32 MB
  bf16_t* upT  = (bf16_t*)(ws + 50765824);   //  32 MB
  bf16_t* dwb  = (bf16_t*)(ws + 84320256);   //  32 MB
  bf16_t* hb   = (bf16_t*)(ws + 117874688);  //  32 MB
  float*  part = (float*)(ws + 151429120);   //  64 MB -> total ~218.5 MB
  bf16_t* gb16 = (bf16_t*)part;  // alias: g dead before down_gemm writes part

  float debiaser = (float)(1.0 / (1e-7 + (1.0 - pow(0.99, 1000.0))));

  prep_mu_thr<<<256, 256, 0, stream>>>(med, aad, gth, debiaser, mu, thr, thrb);
  prep_x_count<<<2048, 256, 0, stream>>>(x, mu, thr, xb, xdb, dense, active);
  transpose_cast_dual<<<dim3(256, 64, 2), 256, 0, stream>>>(gw, gwT, uw, upT);
  cast_bf16<<<8192, 256, 0, stream>>>(dw, dwb);
  c_from_gwT<<<2048, 256, 0, stream>>>(gwT, mu, gb, cj);
  gemm256<2><<<dim3(32, 8), 512, 0, stream>>>(xdb, gwT, thrb, cj, nullptr, gb16, nullptr);
  gemm256<0><<<dim3(32, 8), 512, 0, stream>>>(xb, upT, nullptr, ub, gb16, hb, nullptr);
  gemm256<1><<<dim3(8, 8, 4), 512, 0, stream>>>(hb, dwb, nullptr, nullptr, nullptr, nullptr, part);
  down_reduce<<<4096, 256, 0, stream>>>(part, db, y);
}

// Round 3
// 480.452 us; speedup vs baseline: 1.1867x; 1.0032x over previous
//
#include <hip/hip_runtime.h>
#include <math.h>
#include <stdint.h>

typedef __bf16 bf16_t;
typedef __bf16 bf16x8 __attribute__((ext_vector_type(8)));
typedef __bf16 bf16x4 __attribute__((ext_vector_type(4)));
typedef float f32x4 __attribute__((ext_vector_type(4)));
typedef short s16x8 __attribute__((ext_vector_type(8)));

#define TOKS 2048
#define INF 2048
#define JNF 8192
#define ONF 2048

#define VMW(N) asm volatile("s_waitcnt vmcnt(" #N ")" ::: "memory")
#define LGKM0 asm volatile("s_waitcnt lgkmcnt(0)" ::: "memory")
#define BAR __builtin_amdgcn_s_barrier()

// ---------------- staging helpers (BK=64, half-tile = 128 rows) ----------
// Tile: rows x 64 k bf16, unpadded (row stride 64 elems = 128 B).
// Chunks of 16 B; chunk c: row = c>>3, slot = c&7; slot holds source
// k-quad (slot ^ (row&7)). Fragment ds_read_b128: <=2-way bank alias (free).
// global_load_lds writes lane-contiguous 16B. [conflicts==0 verified R1/R2]
// RACE RULE (R2 post-mortem): every counted-vmcnt window must contain ONLY
// global_load_lds (single class, in-order retirement). No register global
// loads inside the K-loop.

// One half-tile: 128 rows x 64 k = 16 KB = 512 thr x 2 chunks x 16 B.
__device__ __forceinline__ void stage_half(const bf16_t* __restrict__ src, size_t ld,
                                           bf16_t* lds, int tid) {
#pragma unroll
  for (int r = 0; r < 2; ++r) {
    int c = r * 512 + tid;
    int row = c >> 3;
    int kq = (c & 7) ^ (row & 7);
    const bf16_t* g = src + (size_t)row * ld + kq * 8;
    bf16_t* l = lds + (size_t)(r * 512 + (tid & ~63)) * 8;  // wave-uniform base
    __builtin_amdgcn_global_load_lds((const __attribute__((address_space(1))) void*)g,
                                     (__attribute__((address_space(3))) void*)l,
                                     16, 0, 0);
  }
}

__device__ __forceinline__ bf16x8 frag_ld64(const bf16_t* lds, int row, int kq) {
  int slot = kq ^ (row & 7);
  return *(const bf16x8*)&lds[row * 64 + slot * 8];
}

__device__ __forceinline__ void ds_bf(const bf16_t* B, int wn, int m16, int q,
                                      bf16x8 (&bfr)[4][2]) {
#pragma unroll
  for (int ni = 0; ni < 4; ++ni)
#pragma unroll
    for (int ks = 0; ks < 2; ++ks)
      bfr[ni][ks] = frag_ld64(B, wn * 64 + ni * 16 + m16, ks * 4 + q);
}

template <int P>
__device__ __forceinline__ void ds_af(const bf16_t* A, int wm, int m16, int q,
                                      bf16x8 (&af)[2][2]) {
#pragma unroll
  for (int mi2 = 0; mi2 < 2; ++mi2)
#pragma unroll
    for (int ks = 0; ks < 2; ++ks)
      af[mi2][ks] = frag_ld64(A, wm * 128 + P * 32 + mi2 * 16 + m16, ks * 4 + q);
}

template <int P>
__device__ __forceinline__ void mfma_ph(f32x4 (&acc)[8][4], const bf16x8 (&af)[2][2],
                                        const bf16x8 (&bfr)[4][2]) {
  __builtin_amdgcn_s_barrier();
  __builtin_amdgcn_s_setprio(1);
#pragma unroll
  for (int mi2 = 0; mi2 < 2; ++mi2)
#pragma unroll
    for (int ni = 0; ni < 4; ++ni)
#pragma unroll
      for (int ks = 0; ks < 2; ++ks)
        acc[P * 2 + mi2][ni] = __builtin_amdgcn_mfma_f32_16x16x32_bf16(
            af[mi2][ks], bfr[ni][ks], acc[P * 2 + mi2][ni], 0, 0, 0);
  __builtin_amdgcn_s_setprio(0);
}

// MODE 2: in-place threshold masking of a raw-staged A tile. Each thread
// masks exactly the chunks IT staged (same c=r*512+tid mapping), so the
// preceding own-wave vmcnt suffices; LGKM0+BAR after publishes to all.
__device__ __forceinline__ void mask_tile(bf16_t* Atile, const bf16_t* Thl,
                                          int ktile, int tid) {
  const s16x8 ABS = {0x7FFF, 0x7FFF, 0x7FFF, 0x7FFF, 0x7FFF, 0x7FFF, 0x7FFF, 0x7FFF};
#pragma unroll
  for (int r = 0; r < 2; ++r) {
    int c = r * 512 + tid;
    int row = c >> 3;
    int slot = c & 7;
    int kq = slot ^ (row & 7);
    s16x8 a = *(const s16x8*)&Atile[row * 64 + slot * 8];
    s16x8 t = *(const s16x8*)&Thl[ktile + kq * 8];
    s16x8 m = (s16x8)((t - (a & ABS)) >> 15);
    *(s16x8*)&Atile[row * 64 + slot * 8] = a & m;
  }
}

// ---------------- prep kernels ----------------

__global__ __launch_bounds__(256) void prep_mu_thr(
    const float* __restrict__ med, const float* __restrict__ aad,
    const float* __restrict__ gth, float debiaser,
    float* __restrict__ mu, float* __restrict__ thr, bf16_t* __restrict__ thrb) {
  int gid = blockIdx.x * 256 + threadIdx.x;  // 65536 threads
  if (gid < INF) mu[gid] = med[gid] * debiaser;
  int i = gid & (INF - 1);
  float stdv = aad[i] * debiaser / 2.5066282746310002f;  // sqrt(2*pi)
  float tv = gth[gid] * stdv * 45.254833995939045f;      // sqrt(2048)
  thr[gid] = tv;
  thrb[gid] = (bf16_t)tv;
}

// One block per token: bf16 casts of x and (x-mu), plus exact fp32 active count.
__global__ __launch_bounds__(256) void prep_x_count(
    const float* __restrict__ x, const float* __restrict__ mu,
    const float* __restrict__ thr,
    bf16_t* __restrict__ xb, bf16_t* __restrict__ xdb,
    float* __restrict__ dense, float* __restrict__ active) {
  int t = blockIdx.x;
  int tid = threadIdx.x;
  int i0 = tid * 8;
  const float* xrow = x + (size_t)t * INF;
  f32x4 x0 = *(const f32x4*)&xrow[i0];
  f32x4 x1 = *(const f32x4*)&xrow[i0 + 4];
  f32x4 m0 = *(const f32x4*)&mu[i0];
  f32x4 m1 = *(const f32x4*)&mu[i0 + 4];
  f32x4 d0 = x0 - m0, d1 = x1 - m1;
  bf16x8 ox, od;
  ox[0] = (bf16_t)x0[0]; ox[1] = (bf16_t)x0[1]; ox[2] = (bf16_t)x0[2]; ox[3] = (bf16_t)x0[3];
  ox[4] = (bf16_t)x1[0]; ox[5] = (bf16_t)x1[1]; ox[6] = (bf16_t)x1[2]; ox[7] = (bf16_t)x1[3];
  od[0] = (bf16_t)d0[0]; od[1] = (bf16_t)d0[1]; od[2] = (bf16_t)d0[2]; od[3] = (bf16_t)d0[3];
  od[4] = (bf16_t)d1[0]; od[5] = (bf16_t)d1[1]; od[6] = (bf16_t)d1[2]; od[7] = (bf16_t)d1[3];
  *(bf16x8*)&xb[(size_t)t * INF + i0] = ox;
  *(bf16x8*)&xdb[(size_t)t * INF + i0] = od;
  f32x4 a0, a1;
  a0[0] = fabsf(d0[0]); a0[1] = fabsf(d0[1]); a0[2] = fabsf(d0[2]); a0[3] = fabsf(d0[3]);
  a1[0] = fabsf(d1[0]); a1[1] = fabsf(d1[1]); a1[2] = fabsf(d1[2]); a1[3] = fabsf(d1[3]);
  int cnt = 0;
#pragma unroll 4
  for (int n = 0; n < 32; ++n) {
    f32x4 t0 = *(const f32x4*)&thr[(n << 11) + i0];
    f32x4 t1 = *(const f32x4*)&thr[(n << 11) + i0 + 4];
    cnt += (a0[0] > t0[0]) + (a0[1] > t0[1]) + (a0[2] > t0[2]) + (a0[3] > t0[3]);
    cnt += (a1[0] > t1[0]) + (a1[1] > t1[1]) + (a1[2] > t1[2]) + (a1[3] > t1[3]);
  }
  for (int off = 32; off; off >>= 1) cnt += __shfl_down(cnt, off);
  __shared__ int red[4];
  int wv = tid >> 6;
  if ((tid & 63) == 0) red[wv] = cnt;
  __syncthreads();
  if (tid == 0) {
    int tot = red[0] + red[1] + red[2] + red[3];
    active[t] = 256.0f * (float)tot;
    dense[t] = 16777216.0f;
  }
}

// src [INF, JNF] fp32 -> dst [JNF, INF] bf16; z selects (gw,uw). 64x64 tiles.
__global__ __launch_bounds__(256) void transpose_cast_dual(
    const float* __restrict__ src0, bf16_t* __restrict__ dst0,
    const float* __restrict__ src1, bf16_t* __restrict__ dst1) {
  const float* src = blockIdx.z ? src1 : src0;
  bf16_t* dst = blockIdx.z ? dst1 : dst0;
  __shared__ float tile[64][65];
  int j0 = blockIdx.x * 64;
  int i0 = blockIdx.y * 64;
  int tid = threadIdx.x;
  int r = tid >> 4;
  int c4 = (tid & 15) * 4;
#pragma unroll
  for (int rr = 0; rr < 4; ++rr) {
    int row = rr * 16 + r;
    f32x4 v = *(const f32x4*)&src[(size_t)(i0 + row) * JNF + j0 + c4];
    tile[row][c4] = v[0]; tile[row][c4 + 1] = v[1];
    tile[row][c4 + 2] = v[2]; tile[row][c4 + 3] = v[3];
  }
  __syncthreads();
  int jr = tid >> 3;
  int i8 = (tid & 7) * 8;
#pragma unroll
  for (int rr = 0; rr < 2; ++rr) {
    int jrow = rr * 32 + jr;
    bf16x8 o;
#pragma unroll
    for (int k = 0; k < 8; ++k) o[k] = (bf16_t)tile[i8 + k][jrow];
    *(bf16x8*)&dst[(size_t)(j0 + jrow) * INF + i0 + i8] = o;
  }
}

__global__ __launch_bounds__(256) void cast_bf16(
    const float* __restrict__ src, bf16_t* __restrict__ dst) {
  int idx = (blockIdx.x * 256 + threadIdx.x) * 8;
  f32x4 a = *(const f32x4*)&src[idx];
  f32x4 b = *(const f32x4*)&src[idx + 4];
  bf16x8 o;
  o[0] = (bf16_t)a[0]; o[1] = (bf16_t)a[1]; o[2] = (bf16_t)a[2]; o[3] = (bf16_t)a[3];
  o[4] = (bf16_t)b[0]; o[5] = (bf16_t)b[1]; o[6] = (bf16_t)b[2]; o[7] = (bf16_t)b[3];
  *(bf16x8*)&dst[idx] = o;
}

// c[j] = gb[j] + sum_i gwT[j,i]*mu[i]; one wave per j-row, no atomics.
__global__ __launch_bounds__(256) void c_from_gwT(
    const bf16_t* __restrict__ gwT, const float* __restrict__ mu,
    const float* __restrict__ gb, float* __restrict__ c) {
  int j = blockIdx.x * 4 + (threadIdx.x >> 6);
  int lane = threadIdx.x & 63;
  float s = 0.f;
#pragma unroll
  for (int it = 0; it < 4; ++it) {
    int i = it * 512 + lane * 8;
    bf16x8 w = *(const bf16x8*)&gwT[(size_t)j * INF + i];
    f32x4 m0 = *(const f32x4*)&mu[i];
    f32x4 m1 = *(const f32x4*)&mu[i + 4];
    s += (float)w[0] * m0[0] + (float)w[1] * m0[1] + (float)w[2] * m0[2] + (float)w[3] * m0[3];
    s += (float)w[4] * m1[0] + (float)w[5] * m1[1] + (float)w[6] * m1[2] + (float)w[7] * m1[3];
  }
  for (int off = 32; off; off >>= 1) s += __shfl_down(s, off);
  if (lane == 0) c[j] = gb[j] + s;
}

// ------------- unified 256x256 8-phase GEMM, COUNTED vmcnt (T3+T4+T5) -------------
// MODE 0: up   — A=xb,  B=upT, epilogue silu(g)*(<acc>+ub) -> h (bf16)
// MODE 1: down — A=h,   B=dwb, split-K z, epilogue f32 -> part
// MODE 2: gate — A=raw xdb staged via gload_lds, masked IN PLACE in LDS at
//                the K-tile boundary (threshold row cached in Thl); B=gwT,
//                epilogue +cj -> g (bf16). Single vmcnt class (R2 race fix).
//
// Iteration = 2 K-tiles: a=2i (buf0, ph0-3), b=2i+1 (buf1, ph4-7).
// Staging (all modes): ph0 A0(b), ph1 A1(b)+B0(c), ph2 B1(c), ph4 A0(c),
// ph5 A1(c), ph6 B0(d), ph7 B1(d). Boundary waits COUNTED vmcnt(4):
// ph3 drains {B(b),A(b)} leaving {B(c) halves}; ph7 drains {B(c),A(c)}
// leaving {B(d) halves}. Never 0 in steady state (T4).

template <int MODE>
__global__ __launch_bounds__(512) void gemm256(
    const bf16_t* __restrict__ Ag, const bf16_t* __restrict__ Bg,
    const bf16_t* __restrict__ thrv, const float* __restrict__ cvec,
    const bf16_t* __restrict__ gmat, bf16_t* __restrict__ outb,
    float* __restrict__ outf) {
  constexpr size_t LD = (MODE == 1) ? (size_t)JNF : (size_t)INF;
  constexpr int NIT = 16;  // 32 K-tiles of 64
  __shared__ bf16_t Als[2][256 * 64];  // 64 KB
  __shared__ bf16_t Bls[2][256 * 64];  // 64 KB
  __shared__ bf16_t Thl[INF];          // 4 KB (MODE 2 threshold row)
  bf16_t* Als0 = Als[0]; bf16_t* Als1 = Als[1];
  bf16_t* Bls0 = Bls[0]; bf16_t* Bls1 = Bls[1];
  int tid = threadIdx.x;
  int lane = tid & 63;
  int wv = tid >> 6;
  int wm = wv >> 2;  // 0..1 row group (128 rows)
  int wn = wv & 3;   // 0..3 col group (64 cols)
  int m16 = lane & 15, q = lane >> 4;
  int t0 = blockIdx.y * 256;
  int j0 = blockIdx.x * 256;
  int kbeg = (MODE == 1) ? blockIdx.z * 2048 : 0;
  const bf16_t* Arow = Ag + (size_t)t0 * LD + kbeg;
  const bf16_t* Brow = Bg + (size_t)j0 * LD + kbeg;

  f32x4 acc[8][4] = {};
  bf16x8 bfr[4][2];
  bf16x8 af[2][2];

  // ---- prologue: tile0 full, tile1 B; MODE 2 also caches thresholds ----
  if constexpr (MODE == 2) {
    bf16x4 tc = *(const bf16x4*)&thrv[(size_t)blockIdx.x * INF + tid * 4];
    *(bf16x4*)&Thl[tid * 4] = tc;
  }
  stage_half(Brow, LD, Bls0, tid);
  stage_half(Brow + (size_t)128 * LD, LD, Bls0 + 128 * 64, tid);
  stage_half(Arow, LD, Als0, tid);
  stage_half(Arow + (size_t)128 * LD, LD, Als0 + 128 * 64, tid);
  stage_half(Brow + 64, LD, Bls1, tid);
  stage_half(Brow + (size_t)128 * LD + 64, LD, Bls1 + 128 * 64, tid);
  if constexpr (MODE == 2) {
    VMW(0);  // prologue-only full drain (mixed classes OK here)
    LGKM0;   // Thl writes committed
    BAR;
    mask_tile(Als0, Thl, 0, tid);
    LGKM0;
  } else {
    VMW(4);  // need tile0; newer = B(t1)
  }
  BAR;

  for (int i = 0; i < NIT; ++i) {
    const bool S = (i < NIT - 1);
    const int kb = i * 128;  // tile a k0; b:+64 c:+128 d:+192
    // ---- ph0: quadrant 0 of tile a; stage A0(b) ----
    ds_bf(Bls0, wn, m16, q, bfr);
    ds_af<0>(Als0, wm, m16, q, af);
    stage_half(Arow + kb + 64, LD, Als1, tid);
    mfma_ph<0>(acc, af, bfr); BAR;
    // ---- ph1: stage A1(b); B0(c) ----
    ds_af<1>(Als0, wm, m16, q, af);
    stage_half(Arow + (size_t)128 * LD + kb + 64, LD, Als1 + 128 * 64, tid);
    if (S) stage_half(Brow + kb + 128, LD, Bls0, tid);
    mfma_ph<1>(acc, af, bfr); BAR;
    // ---- ph2: stage B1(c) ----
    ds_af<2>(Als0, wm, m16, q, af);
    if (S) stage_half(Brow + (size_t)128 * LD + kb + 128, LD, Bls0 + 128 * 64, tid);
    mfma_ph<2>(acc, af, bfr); BAR;
    // ---- ph3: boundary wait (counted); MODE 2 masks tile b in place ----
    ds_af<3>(Als0, wm, m16, q, af);
    mfma_ph<3>(acc, af, bfr);
    if (S) { VMW(4); } else { VMW(0); }
    if constexpr (MODE == 2) {
      mask_tile(Als1, Thl, kb + 64, tid);
      LGKM0;
    }
    BAR;
    // ---- ph4: quadrant 0 of tile b; stage A0(c) ----
    ds_bf(Bls1, wn, m16, q, bfr);
    ds_af<0>(Als1, wm, m16, q, af);
    if (S) stage_half(Arow + kb + 128, LD, Als0, tid);
    mfma_ph<4>(acc, af, bfr); BAR;
    // ---- ph5: stage A1(c) ----
    ds_af<1>(Als1, wm, m16, q, af);
    if (S) stage_half(Arow + (size_t)128 * LD + kb + 128, LD, Als0 + 128 * 64, tid);
    mfma_ph<5>(acc, af, bfr); BAR;
    // ---- ph6: stage B0(d) ----
    ds_af<2>(Als1, wm, m16, q, af);
    if (S) stage_half(Brow + kb + 192, LD, Bls1, tid);
    mfma_ph<6>(acc, af, bfr); BAR;
    // ---- ph7: stage B1(d); boundary wait (counted); MODE 2 masks tile c ----
    ds_af<3>(Als1, wm, m16, q, af);
    if (S) stage_half(Brow + (size_t)128 * LD + kb + 192, LD, Bls1 + 128 * 64, tid);
    mfma_ph<7>(acc, af, bfr);
    if (S) { VMW(4); } else { VMW(0); }
    if constexpr (MODE == 2) {
      if (S) {
        mask_tile(Als0, Thl, kb + 128, tid);
        LGKM0;
      }
    }
    BAR;
  }

  // ---- epilogue ----
  int cb = j0 + wn * 64;
  int rb = t0 + wm * 128;
  if constexpr (MODE == 1) {
    float* dst = outf + (size_t)blockIdx.z * ((size_t)TOKS * ONF);
#pragma unroll
    for (int mi = 0; mi < 8; ++mi)
#pragma unroll
      for (int ni = 0; ni < 4; ++ni) {
        int col = cb + ni * 16 + m16;
#pragma unroll
        for (int r = 0; r < 4; ++r) {
          int row = rb + mi * 16 + q * 4 + r;
          dst[(size_t)row * ONF + col] = acc[mi][ni][r];
        }
      }
  } else if constexpr (MODE == 0) {
#pragma unroll
    for (int mi = 0; mi < 8; ++mi)
#pragma unroll
      for (int ni = 0; ni < 4; ++ni) {
        int col = cb + ni * 16 + m16;
        float bias = cvec[col];
#pragma unroll
        for (int r = 0; r < 4; ++r) {
          int row = rb + mi * 16 + q * 4 + r;
          float upv = acc[mi][ni][r] + bias;
          float gv = (float)gmat[(size_t)row * JNF + col];
          float hv = (gv / (1.f + expf(-gv))) * upv;
          outb[(size_t)row * JNF + col] = (bf16_t)hv;
        }
      }
  } else {
#pragma unroll
    for (int mi = 0; mi < 8; ++mi)
#pragma unroll
      for (int ni = 0; ni < 4; ++ni) {
        int col = cb + ni * 16 + m16;
        float cadd = cvec[col];
#pragma unroll
        for (int r = 0; r < 4; ++r) {
          int row = rb + mi * 16 + q * 4 + r;
          outb[(size_t)row * JNF + col] = (bf16_t)(acc[mi][ni][r] + cadd);
        }
      }
  }
}

__global__ __launch_bounds__(256) void down_reduce(
    const float* __restrict__ part, const float* __restrict__ db,
    float* __restrict__ y) {
  int idx = (blockIdx.x * 256 + threadIdx.x) * 4;
  f32x4 a = *(const f32x4*)&part[idx];
  f32x4 b = *(const f32x4*)&part[idx + 4194304];
  f32x4 c = *(const f32x4*)&part[idx + 2 * 4194304];
  f32x4 d = *(const f32x4*)&part[idx + 3 * 4194304];
  f32x4 bias = *(const f32x4*)&db[idx & (ONF - 1)];
  *(f32x4*)&y[idx] = a + b + c + d + bias;
}

// ---------------- launcher ----------------

extern "C" void kernel_launch(void* const* d_in, const int* in_sizes, int n_in,
                              void* d_out, int out_size, void* d_ws, size_t ws_size,
                              hipStream_t stream) {
  (void)in_sizes; (void)n_in; (void)out_size; (void)ws_size;
  const float* x   = (const float*)d_in[0];
  const float* gw  = (const float*)d_in[1];
  const float* gb  = (const float*)d_in[2];
  const float* gth = (const float*)d_in[3];
  const float* med = (const float*)d_in[4];
  const float* aad = (const float*)d_in[5];
  const float* uw  = (const float*)d_in[6];
  const float* ub  = (const float*)d_in[7];
  const float* dw  = (const float*)d_in[8];
  const float* db  = (const float*)d_in[9];

  float* out = (float*)d_out;
  float* y = out;                       // [2048,2048]
  float* dense = out + 4194304;         // [2048]
  float* active = dense + 2048;         // [2048]

  char* ws = (char*)d_ws;
  float*  mu   = (float*)(ws + 0);           //   8 KB
  float*  thr  = (float*)(ws + 8192);        // 256 KB (fp32, exact count)
  bf16_t* thrb = (bf16_t*)(ws + 270336);     // 128 KB (bf16 bits)
  float*  cj   = (float*)(ws + 401408);      //  32 KB
  bf16_t* xb   = (bf16_t*)(ws + 434176);     //   8 MB
  bf16_t* xdb  = (bf16_t*)(ws + 8822784);    //   8 MB
  bf16_t* gwT  = (bf16_t*)(ws + 17211392);   //  32 MB
  bf16_t* upT  = (bf16_t*)(ws + 50765824);   //  32 MB
  bf16_t* dwb  = (bf16_t*)(ws + 84320256);   //  32 MB
  bf16_t* hb   = (bf16_t*)(ws + 117874688);  //  32 MB
  float*  part = (float*)(ws + 151429120);   //  64 MB -> total ~218.5 MB
  bf16_t* gb16 = (bf16_t*)part;  // alias: g dead before down_gemm writes part

  float debiaser = (float)(1.0 / (1e-7 + (1.0 - pow(0.99, 1000.0))));

  prep_mu_thr<<<256, 256, 0, stream>>>(med, aad, gth, debiaser, mu, thr, thrb);
  prep_x_count<<<2048, 256, 0, stream>>>(x, mu, thr, xb, xdb, dense, active);
  transpose_cast_dual<<<dim3(128, 32, 2), 256, 0, stream>>>(gw, gwT, uw, upT);
  cast_bf16<<<8192, 256, 0, stream>>>(dw, dwb);
  c_from_gwT<<<2048, 256, 0, stream>>>(gwT, mu, gb, cj);
  gemm256<2><<<dim3(32, 8), 512, 0, stream>>>(xdb, gwT, thrb, cj, nullptr, gb16, nullptr);
  gemm256<0><<<dim3(32, 8), 512, 0, stream>>>(xb, upT, nullptr, ub, gb16, hb, nullptr);
  gemm256<1><<<dim3(8, 8, 4), 512, 0, stream>>>(hb, dwb, nullptr, nullptr, nullptr, nullptr, part);
  down_reduce<<<4096, 256, 0, stream>>>(part, db, y);
}